// Round 1
// baseline (205.963 us; speedup 1.0000x reference)
//
#include <hip/hip_runtime.h>
#include <hip/hip_bf16.h>

typedef __attribute__((ext_vector_type(8))) short bf16x8;
typedef __attribute__((ext_vector_type(4))) float f32x4;

// RNE float -> bf16 bits (values are finite, no NaN handling needed)
static __device__ __forceinline__ ushort f2b(float f) {
    unsigned u = __float_as_uint(f);
    unsigned r = (u + 0x7fffu + ((u >> 16) & 1u)) >> 16;
    return (ushort)r;
}

// ---------------------------------------------------------------------------
// prep: per (b,d) row of x[64][256][196]: compute mean, write centered bf16
// into xc[64][256][224] (k=196..223 zero-padded), and var_d (+1e-7) for trace.
// One wave per row, 4 waves per block.
// ---------------------------------------------------------------------------
__global__ __launch_bounds__(256) void prep_kernel(
    const float* __restrict__ x, ushort* __restrict__ xc, float* __restrict__ var)
{
    const int t  = threadIdx.x;
    const int wv = t >> 6, l = t & 63;
    const int rowid = blockIdx.x * 4 + wv;     // b*256 + d, 0..16383
    const float* xr = x + (size_t)rowid * 196;

    float x0 = xr[l];
    float x1 = xr[l + 64];
    float x2 = xr[l + 128];                    // 128+63 = 191 < 196, all valid
    float x3 = (l < 4) ? xr[l + 192] : 0.0f;

    float s1 = x0 + x1 + x2 + x3;
    float s2 = x0*x0 + x1*x1 + x2*x2 + x3*x3;
    #pragma unroll
    for (int off = 32; off; off >>= 1) {
        s1 += __shfl_xor(s1, off);
        s2 += __shfl_xor(s2, off);
    }
    const float mean = s1 * (1.0f / 196.0f);
    if (l == 0) var[rowid] = s2 * (1.0f / 196.0f) - mean * mean + 1e-7f;

    ushort* xcr = xc + (size_t)rowid * 224;
    xcr[l]       = f2b(x0 - mean);
    xcr[l + 64]  = f2b(x1 - mean);
    xcr[l + 128] = f2b(x2 - mean);
    if (l < 4)        xcr[l + 192] = f2b(x3 - mean);
    else if (l < 32)  xcr[l + 192] = 0;        // zero pad 196..223
}

// ---------------------------------------------------------------------------
// finalize: trace[b] = sum_d var_d  -> invtrace, sqrt(trace)
// ---------------------------------------------------------------------------
__global__ __launch_bounds__(256) void finalize_norm(
    const float* __restrict__ var, float* __restrict__ invtr, float* __restrict__ sqn)
{
    __shared__ float ws4[4];
    const int b = blockIdx.x, t = threadIdx.x;
    float v = var[b * 256 + t];
    #pragma unroll
    for (int off = 32; off; off >>= 1) v += __shfl_xor(v, off);
    if ((t & 63) == 0) ws4[t >> 6] = v;
    __syncthreads();
    if (t == 0) {
        float tr = ws4[0] + ws4[1] + ws4[2] + ws4[3];
        invtr[b] = 1.0f / tr;
        sqn[b]   = sqrtf(tr);
    }
}

// ---------------------------------------------------------------------------
// Batched NT GEMM on symmetric operands: C[b] = A[b] * Bt[b]^T  (256x256xK)
// A, Bt row-major [256][lda] bf16, batch stride 256*lda. Output 256x256 bf16.
// modes: 0 = COV  (C = Y0 = (acc/196 + 1e-7 I)*invtr;  C2 = 1.5I - 0.5*Y0)
//        1 = T    (C = 1.5I - 0.5*acc)
//        2 = PLAIN(C = acc)
//        3 = FINAL(C = acc * sqrtnorm[b])
// 64x64 tile per block, 4 waves, mfma_f32_16x16x32_bf16.
// ---------------------------------------------------------------------------
__global__ __launch_bounds__(256) void gemm_bt(
    const ushort* __restrict__ A, const ushort* __restrict__ Bt,
    ushort* __restrict__ C, ushort* __restrict__ C2,
    const float* __restrict__ scal, int mode, int K, int lda)
{
    __shared__ ushort As[64][40];   // +8 pad: 80B rows, 16B aligned, 2-way max
    __shared__ ushort Bs[64][40];

    const int b  = blockIdx.y;
    const int i0 = (blockIdx.x >> 2) * 64;
    const int j0 = (blockIdx.x & 3) * 64;
    const size_t mstride = (size_t)256 * lda;
    const ushort* Ab  = A  + (size_t)b * mstride;
    const ushort* Btb = Bt + (size_t)b * mstride;

    const int t   = threadIdx.x;
    const int row = t >> 2;        // 0..63
    const int seg = t & 3;         // 16B segment within 64B row chunk
    const int wv  = t >> 6;        // wave 0..3
    const int l   = t & 63;
    const int li  = l & 15, hi = l >> 4;

    f32x4 acc[4];
    #pragma unroll
    for (int c = 0; c < 4; ++c) acc[c] = (f32x4){0.f, 0.f, 0.f, 0.f};

    for (int kk = 0; kk < K; kk += 32) {
        *(bf16x8*)&As[row][seg * 8] =
            *(const bf16x8*)(Ab  + (size_t)(i0 + row) * lda + kk + seg * 8);
        *(bf16x8*)&Bs[row][seg * 8] =
            *(const bf16x8*)(Btb + (size_t)(j0 + row) * lda + kk + seg * 8);
        __syncthreads();
        bf16x8 a = *(const bf16x8*)&As[wv * 16 + li][hi * 8];
        #pragma unroll
        for (int c = 0; c < 4; ++c) {
            bf16x8 bb = *(const bf16x8*)&Bs[c * 16 + li][hi * 8];
            acc[c] = __builtin_amdgcn_mfma_f32_16x16x32_bf16(a, bb, acc[c], 0, 0, 0);
        }
        __syncthreads();
    }

    const float sc = (scal != nullptr) ? scal[b] : 0.0f;
    ushort* Cb  = C + (size_t)b * 65536;
    ushort* C2b = (C2 != nullptr) ? (C2 + (size_t)b * 65536) : nullptr;
    #pragma unroll
    for (int c = 0; c < 4; ++c) {
        #pragma unroll
        for (int r = 0; r < 4; ++r) {
            const int gi = i0 + wv * 16 + hi * 4 + r;
            const int gj = j0 + c * 16 + li;
            const float v = acc[c][r];
            const size_t idx = (size_t)gi * 256 + gj;
            if (mode == 0) {
                float y0 = (v * (1.0f / 196.0f) + ((gi == gj) ? 1e-7f : 0.0f)) * sc;
                Cb[idx]  = f2b(y0);
                C2b[idx] = f2b(((gi == gj) ? 1.5f : 0.0f) - 0.5f * y0);
            } else if (mode == 1) {
                Cb[idx] = f2b(((gi == gj) ? 1.5f : 0.0f) - 0.5f * v);
            } else if (mode == 2) {
                Cb[idx] = f2b(v);
            } else {
                Cb[idx] = f2b(v * sc);
            }
        }
    }
}

// ---------------------------------------------------------------------------
// gather lower-tri (row-major) of final Y into tri[64][32896] bf16
// ---------------------------------------------------------------------------
__global__ __launch_bounds__(256) void gather_tri(
    const ushort* __restrict__ Y, ushort* __restrict__ tri)
{
    const int r = blockIdx.x, b = blockIdx.y, c = threadIdx.x;
    if (c <= r)
        tri[(size_t)b * 32896 + ((size_t)r * (r + 1)) / 2 + c] =
            Y[(size_t)b * 65536 + r * 256 + c];
}

// ---------------------------------------------------------------------------
// FC: partial[split][64][384] += tri[64][K] * W[365][K]^T over this split's K
// K = 32896 = 1028 steps of 32; 64 splits (first 4 take 17 steps, rest 16).
// W is fp32, converted to bf16 on load (read exactly once).
// ---------------------------------------------------------------------------
__global__ __launch_bounds__(256) void fc_gemm(
    const ushort* __restrict__ tri, const float* __restrict__ W,
    float* __restrict__ partial)
{
    __shared__ ushort As[64][40];
    __shared__ ushort Bs[64][40];

    const int ntile = blockIdx.x;              // 0..5
    const int split = blockIdx.y;              // 0..63
    const int steps = 16 + (split < 4 ? 1 : 0);
    const int step0 = split * 16 + (split < 4 ? split : 4);

    const int t   = threadIdx.x;
    const int row = t >> 2, seg = t & 3;
    const int wv  = t >> 6, l = t & 63;
    const int li  = l & 15, hi = l >> 4;
    const int n   = ntile * 64 + row;

    f32x4 acc[4];
    #pragma unroll
    for (int c = 0; c < 4; ++c) acc[c] = (f32x4){0.f, 0.f, 0.f, 0.f};

    for (int s = 0; s < steps; ++s) {
        const int kk = (step0 + s) * 32;
        *(bf16x8*)&As[row][seg * 8] =
            *(const bf16x8*)(tri + (size_t)row * 32896 + kk + seg * 8);
        bf16x8 pk;
        if (n < 365) {
            const float* wp = W + (size_t)n * 32896 + kk + seg * 8;
            float4 f0 = *(const float4*)wp;
            float4 f1 = *(const float4*)(wp + 4);
            pk[0] = (short)f2b(f0.x); pk[1] = (short)f2b(f0.y);
            pk[2] = (short)f2b(f0.z); pk[3] = (short)f2b(f0.w);
            pk[4] = (short)f2b(f1.x); pk[5] = (short)f2b(f1.y);
            pk[6] = (short)f2b(f1.z); pk[7] = (short)f2b(f1.w);
        } else {
            pk = (bf16x8){0,0,0,0,0,0,0,0};
        }
        *(bf16x8*)&Bs[row][seg * 8] = pk;
        __syncthreads();
        bf16x8 a = *(const bf16x8*)&As[wv * 16 + li][hi * 8];
        #pragma unroll
        for (int c = 0; c < 4; ++c) {
            bf16x8 bb = *(const bf16x8*)&Bs[c * 16 + li][hi * 8];
            acc[c] = __builtin_amdgcn_mfma_f32_16x16x32_bf16(a, bb, acc[c], 0, 0, 0);
        }
        __syncthreads();
    }

    #pragma unroll
    for (int c = 0; c < 4; ++c) {
        #pragma unroll
        for (int r = 0; r < 4; ++r) {
            const int i = wv * 16 + hi * 4 + r;          // batch 0..63
            const int j = ntile * 64 + c * 16 + li;      // 0..383
            partial[((size_t)split * 64 + i) * 384 + j] = acc[c][r];
        }
    }
}

__global__ void fc_reduce(const float* __restrict__ partial,
                          const float* __restrict__ bias, float* __restrict__ out)
{
    const int idx = blockIdx.x * 256 + threadIdx.x;
    if (idx >= 64 * 365) return;
    const int b = idx / 365, n = idx % 365;
    float s = bias[n];
    #pragma unroll 4
    for (int sp = 0; sp < 64; ++sp)
        s += partial[((size_t)sp * 64 + b) * 384 + n];
    out[idx] = s;
}

// ---------------------------------------------------------------------------
extern "C" void kernel_launch(void* const* d_in, const int* in_sizes, int n_in,
                              void* d_out, int out_size, void* d_ws, size_t ws_size,
                              hipStream_t stream)
{
    const float* x   = (const float*)d_in[0];
    const float* fcw = (const float*)d_in[1];
    const float* fcb = (const float*)d_in[2];
    float* out = (float*)d_out;
    char* ws = (char*)d_ws;

    const size_t MS = (size_t)64 * 256 * 256 * 2;   // 8,388,608 per matrix buffer
    ushort* w0 = (ushort*)(ws + 0 * MS);
    ushort* w1 = (ushort*)(ws + 1 * MS);
    ushort* w2 = (ushort*)(ws + 2 * MS);
    ushort* w3 = (ushort*)(ws + 3 * MS);
    ushort* w4 = (ushort*)(ws + 4 * MS);
    ushort* xc = (ushort*)(ws + 5 * MS);                       // 7,340,032
    float*  var    = (float*)(ws + 5 * MS + 7340032);          // 65,536
    float*  invtr  = (float*)(ws + 5 * MS + 7340032 + 65536);  // 256
    float*  sqn    = (float*)(ws + 5 * MS + 7340032 + 65536 + 256);
    ushort* tri    = (ushort*)(ws + 5 * MS + 7340032 + 65536 + 512);       // 4,210,688
    float*  partial= (float*)(ws + 5 * MS + 7340032 + 65536 + 512 + 4210688);

    prep_kernel<<<4096, 256, 0, stream>>>(x, xc, var);
    finalize_norm<<<64, 256, 0, stream>>>(var, invtr, sqn);

    dim3 g(16, 64);
    // cov: Y0 -> w0, T0 (= Z1) -> w1
    gemm_bt<<<g, 256, 0, stream>>>(xc, xc, w0, w1, invtr, 0, 224, 224);
    // Y1 = Y0*T0 -> w2
    gemm_bt<<<g, 256, 0, stream>>>(w0, w1, w2, nullptr, nullptr, 2, 256, 256);
    // iter2: Y=w2 Z=w1 | T -> w0 ; Y -> w3 ; Z -> w4
    gemm_bt<<<g, 256, 0, stream>>>(w1, w2, w0, nullptr, nullptr, 1, 256, 256);
    gemm_bt<<<g, 256, 0, stream>>>(w2, w0, w3, nullptr, nullptr, 2, 256, 256);
    gemm_bt<<<g, 256, 0, stream>>>(w0, w1, w4, nullptr, nullptr, 2, 256, 256);
    // iter3: Y=w3 Z=w4 | T -> w0 ; Y -> w1 ; Z -> w2
    gemm_bt<<<g, 256, 0, stream>>>(w4, w3, w0, nullptr, nullptr, 1, 256, 256);
    gemm_bt<<<g, 256, 0, stream>>>(w3, w0, w1, nullptr, nullptr, 2, 256, 256);
    gemm_bt<<<g, 256, 0, stream>>>(w0, w4, w2, nullptr, nullptr, 2, 256, 256);
    // iter4: Y=w1 Z=w2 | T -> w0 ; Y -> w3 ; Z -> w4
    gemm_bt<<<g, 256, 0, stream>>>(w2, w1, w0, nullptr, nullptr, 1, 256, 256);
    gemm_bt<<<g, 256, 0, stream>>>(w1, w0, w3, nullptr, nullptr, 2, 256, 256);
    gemm_bt<<<g, 256, 0, stream>>>(w0, w2, w4, nullptr, nullptr, 2, 256, 256);
    // iter5: Y=w3 Z=w4 | T -> w0 ; Yfinal = (Y*T)*sqrt(norm) -> w1
    gemm_bt<<<g, 256, 0, stream>>>(w4, w3, w0, nullptr, nullptr, 1, 256, 256);
    gemm_bt<<<g, 256, 0, stream>>>(w3, w0, w1, nullptr, sqn, 3, 256, 256);

    gather_tri<<<dim3(256, 64), 256, 0, stream>>>(w1, tri);
    fc_gemm<<<dim3(6, 64), 256, 0, stream>>>(tri, fcw, partial);
    fc_reduce<<<(64 * 365 + 255) / 256, 256, 0, stream>>>(partial, fcb, out);
}

// Round 2
// 145.970 us; speedup vs baseline: 1.4110x; 1.4110x over previous
//
#include <hip/hip_runtime.h>
#include <hip/hip_bf16.h>

typedef __attribute__((ext_vector_type(8))) short bf16x8;
typedef __attribute__((ext_vector_type(4))) float f32x4;

// RNE float -> bf16 bits
static __device__ __forceinline__ ushort f2b(float f) {
    unsigned u = __float_as_uint(f);
    return (ushort)((u + 0x7fffu + ((u >> 16) & 1u)) >> 16);
}

static __device__ __forceinline__ void gload16(const void* g, void* lds) {
    __builtin_amdgcn_global_load_lds(
        (const __attribute__((address_space(1))) unsigned int*)g,
        (__attribute__((address_space(3))) unsigned int*)lds, 16, 0, 0);
}

// ---------------------------------------------------------------------------
// prep: per (b,d) row of x[64][256][196]: mean-center, write bf16 into
// xc[64][256][256] (k=196..255 zero), var_d (+1e-7) for trace.
// ---------------------------------------------------------------------------
__global__ __launch_bounds__(256) void prep_kernel(
    const float* __restrict__ x, ushort* __restrict__ xc, float* __restrict__ var)
{
    const int t = threadIdx.x, wv = t >> 6, l = t & 63;
    const int rowid = blockIdx.x * 4 + wv;     // b*256 + d
    const float* xr = x + (size_t)rowid * 196;

    float x0 = xr[l];
    float x1 = xr[l + 64];
    float x2 = xr[l + 128];
    float x3 = (l < 4) ? xr[l + 192] : 0.0f;

    float s1 = x0 + x1 + x2 + x3;
    float s2 = x0*x0 + x1*x1 + x2*x2 + x3*x3;
    #pragma unroll
    for (int off = 32; off; off >>= 1) {
        s1 += __shfl_xor(s1, off);
        s2 += __shfl_xor(s2, off);
    }
    const float mean = s1 * (1.0f / 196.0f);
    if (l == 0) var[rowid] = s2 * (1.0f / 196.0f) - mean * mean + 1e-7f;

    ushort* xcr = xc + (size_t)rowid * 256;
    xcr[l]       = f2b(x0 - mean);
    xcr[l + 64]  = f2b(x1 - mean);
    xcr[l + 128] = f2b(x2 - mean);
    xcr[l + 192] = (l < 4) ? f2b(x3 - mean) : (ushort)0;   // zero pad 196..255
}

__global__ __launch_bounds__(256) void finalize_norm(
    const float* __restrict__ var, float* __restrict__ invtr, float* __restrict__ sqn)
{
    __shared__ float ws4[4];
    const int b = blockIdx.x, t = threadIdx.x;
    float v = var[b * 256 + t];
    #pragma unroll
    for (int off = 32; off; off >>= 1) v += __shfl_xor(v, off);
    if ((t & 63) == 0) ws4[t >> 6] = v;
    __syncthreads();
    if (t == 0) {
        float tr = ws4[0] + ws4[1] + ws4[2] + ws4[3];
        invtr[b] = 1.0f / tr;
        sqn[b]   = sqrtf(tr);
    }
}

// ---------------------------------------------------------------------------
// Batched NT GEMM on symmetric operands, 128x128 tile, BK=32, 4 waves,
// global_load_lds staging, 2-phase double-buffered LDS. K fixed = 256.
// MODE 0: cov     : C  = Y0 = (acc/196 + 1e-7 I)*invtr[b];  C2 = 1.5I - 0.5*Y0
// MODE 1: T       : C  = 1.5I - 0.5*acc
// MODE 2: pair    : bb<64: acc = A[b]*Bt^T -> C;  bb>=64: acc = A2[b]*Bt^T -> C2
// MODE 3: finaltri: tri(C) = lower-tri of acc*sqn[b]
// ---------------------------------------------------------------------------
template<int MODE>
__global__ __launch_bounds__(256) void gemm_ns(
    const ushort* __restrict__ A, const ushort* __restrict__ A2,
    const ushort* __restrict__ Bt,
    ushort* __restrict__ C, ushort* __restrict__ C2,
    const float* __restrict__ scal)
{
    __shared__ ushort As[2][128][32];
    __shared__ ushort Bs[2][128][32];

    const int bb = blockIdx.y, b = bb & 63;
    const int i0 = (blockIdx.x >> 1) * 128;
    const int j0 = (blockIdx.x & 1) * 128;
    const ushort* Ab  = ((MODE == 2 && bb >= 64) ? A2 : A) + (size_t)b * 65536;
    const ushort* Btb = Bt + (size_t)b * 65536;

    const int t  = threadIdx.x, wv = t >> 6, l = t & 63;
    const int li = l & 15, hi = l >> 4;
    const int wr = wv >> 1, wc = wv & 1;
    const int srow = wv * 16 + (l >> 2);       // staging row for chunk c0 = wv*64+l
    const int scol = (l & 3) * 8;              // staging col (elements)

    f32x4 acc[4][4];
    #pragma unroll
    for (int m = 0; m < 4; ++m)
        #pragma unroll
        for (int n = 0; n < 4; ++n) acc[m][n] = (f32x4){0.f, 0.f, 0.f, 0.f};

    // stage A/B tile for k-step kk into buffer bufo (linear [128][32] layout)
#define STAGE(bufo, kk) do {                                                        \
    gload16(Ab  + (size_t)(i0 +      srow) * 256 + (kk) + scol,                     \
            (char*)&As[bufo][0][0] + wv * 1024);                                    \
    gload16(Ab  + (size_t)(i0 + 64 + srow) * 256 + (kk) + scol,                     \
            (char*)&As[bufo][0][0] + 4096 + wv * 1024);                             \
    gload16(Btb + (size_t)(j0 +      srow) * 256 + (kk) + scol,                     \
            (char*)&Bs[bufo][0][0] + wv * 1024);                                    \
    gload16(Btb + (size_t)(j0 + 64 + srow) * 256 + (kk) + scol,                     \
            (char*)&Bs[bufo][0][0] + 4096 + wv * 1024);                             \
} while (0)

    STAGE(0, 0);
    __syncthreads();
    #pragma unroll
    for (int tk = 0; tk < 8; ++tk) {
        const int bo = tk & 1;
        if (tk < 7) STAGE(bo ^ 1, (tk + 1) * 32);
        bf16x8 af[4], bfr[4];
        #pragma unroll
        for (int m = 0; m < 4; ++m)
            af[m] = *(const bf16x8*)&As[bo][wr * 64 + m * 16 + li][hi * 8];
        #pragma unroll
        for (int n = 0; n < 4; ++n)
            bfr[n] = *(const bf16x8*)&Bs[bo][wc * 64 + n * 16 + li][hi * 8];
        #pragma unroll
        for (int m = 0; m < 4; ++m)
            #pragma unroll
            for (int n = 0; n < 4; ++n)
                acc[m][n] = __builtin_amdgcn_mfma_f32_16x16x32_bf16(
                    af[m], bfr[n], acc[m][n], 0, 0, 0);
        __syncthreads();
    }
#undef STAGE

    const float sc = (MODE == 0 || MODE == 3) ? scal[b] : 0.0f;

    if (MODE == 3) {
        ushort* trib = C + (size_t)b * 32896;
        #pragma unroll
        for (int m = 0; m < 4; ++m)
            #pragma unroll
            for (int n = 0; n < 4; ++n)
                #pragma unroll
                for (int r = 0; r < 4; ++r) {
                    const int gi = i0 + wr * 64 + m * 16 + hi * 4 + r;
                    const int gj = j0 + wc * 64 + n * 16 + li;
                    if (gj <= gi)
                        trib[(gi * (gi + 1)) / 2 + gj] = f2b(acc[m][n][r] * sc);
                }
    } else {
        ushort* Cb  = ((MODE == 2 && bb >= 64) ? C2 : C) + (size_t)b * 65536;
        ushort* C2b = (MODE == 0) ? (C2 + (size_t)b * 65536) : nullptr;
        #pragma unroll
        for (int m = 0; m < 4; ++m)
            #pragma unroll
            for (int n = 0; n < 4; ++n)
                #pragma unroll
                for (int r = 0; r < 4; ++r) {
                    const int gi = i0 + wr * 64 + m * 16 + hi * 4 + r;
                    const int gj = j0 + wc * 64 + n * 16 + li;
                    const float v = acc[m][n][r];
                    const size_t idx = (size_t)gi * 256 + gj;
                    if (MODE == 0) {
                        float y0 = (v * (1.0f / 196.0f) + ((gi == gj) ? 1e-7f : 0.0f)) * sc;
                        Cb[idx]  = f2b(y0);
                        C2b[idx] = f2b(((gi == gj) ? 1.5f : 0.0f) - 0.5f * y0);
                    } else if (MODE == 1) {
                        Cb[idx] = f2b(((gi == gj) ? 1.5f : 0.0f) - 0.5f * v);
                    } else {
                        Cb[idx] = f2b(v);
                    }
                }
    }
}

// ---------------------------------------------------------------------------
// FC: partial[split][64][384] = tri[64][K] * W[365][K]^T over this split's K
// ---------------------------------------------------------------------------
__global__ __launch_bounds__(256) void fc_gemm(
    const ushort* __restrict__ tri, const float* __restrict__ W,
    float* __restrict__ partial)
{
    __shared__ ushort As[64][40];
    __shared__ ushort Bs[64][40];

    const int ntile = blockIdx.x;              // 0..5
    const int split = blockIdx.y;              // 0..63
    const int steps = 16 + (split < 4 ? 1 : 0);
    const int step0 = split * 16 + (split < 4 ? split : 4);

    const int t   = threadIdx.x;
    const int row = t >> 2, seg = t & 3;
    const int wv  = t >> 6, l = t & 63;
    const int li  = l & 15, hi = l >> 4;
    const int n   = ntile * 64 + row;

    f32x4 acc[4];
    #pragma unroll
    for (int c = 0; c < 4; ++c) acc[c] = (f32x4){0.f, 0.f, 0.f, 0.f};

    for (int s = 0; s < steps; ++s) {
        const int kk = (step0 + s) * 32;
        *(bf16x8*)&As[row][seg * 8] =
            *(const bf16x8*)(tri + (size_t)row * 32896 + kk + seg * 8);
        bf16x8 pk;
        if (n < 365) {
            const float* wp = W + (size_t)n * 32896 + kk + seg * 8;
            float4 f0 = *(const float4*)wp;
            float4 f1 = *(const float4*)(wp + 4);
            pk[0] = (short)f2b(f0.x); pk[1] = (short)f2b(f0.y);
            pk[2] = (short)f2b(f0.z); pk[3] = (short)f2b(f0.w);
            pk[4] = (short)f2b(f1.x); pk[5] = (short)f2b(f1.y);
            pk[6] = (short)f2b(f1.z); pk[7] = (short)f2b(f1.w);
        } else {
            pk = (bf16x8){0,0,0,0,0,0,0,0};
        }
        *(bf16x8*)&Bs[row][seg * 8] = pk;
        __syncthreads();
        bf16x8 a = *(const bf16x8*)&As[wv * 16 + li][hi * 8];
        #pragma unroll
        for (int c = 0; c < 4; ++c) {
            bf16x8 bb = *(const bf16x8*)&Bs[c * 16 + li][hi * 8];
            acc[c] = __builtin_amdgcn_mfma_f32_16x16x32_bf16(a, bb, acc[c], 0, 0, 0);
        }
        __syncthreads();
    }

    #pragma unroll
    for (int c = 0; c < 4; ++c) {
        #pragma unroll
        for (int r = 0; r < 4; ++r) {
            const int i = wv * 16 + hi * 4 + r;          // batch
            const int j = ntile * 64 + c * 16 + li;      // class
            partial[((size_t)split * 64 + i) * 384 + j] = acc[c][r];
        }
    }
}

__global__ void fc_reduce(const float* __restrict__ partial,
                          const float* __restrict__ bias, float* __restrict__ out)
{
    const int idx = blockIdx.x * 256 + threadIdx.x;
    if (idx >= 64 * 365) return;
    const int b = idx / 365, n = idx % 365;
    float s = bias[n];
    #pragma unroll 4
    for (int sp = 0; sp < 64; ++sp)
        s += partial[((size_t)sp * 64 + b) * 384 + n];
    out[idx] = s;
}

// ---------------------------------------------------------------------------
extern "C" void kernel_launch(void* const* d_in, const int* in_sizes, int n_in,
                              void* d_out, int out_size, void* d_ws, size_t ws_size,
                              hipStream_t stream)
{
    const float* x   = (const float*)d_in[0];
    const float* fcw = (const float*)d_in[1];
    const float* fcb = (const float*)d_in[2];
    float* out = (float*)d_out;
    char* ws = (char*)d_ws;

    const size_t MS = (size_t)64 * 256 * 256 * 2;   // 8 MiB per matrix buffer
    ushort* w0 = (ushort*)(ws + 0 * MS);
    ushort* w1 = (ushort*)(ws + 1 * MS);
    ushort* w2 = (ushort*)(ws + 2 * MS);
    ushort* w3 = (ushort*)(ws + 3 * MS);
    ushort* w4 = (ushort*)(ws + 4 * MS);
    ushort* xc = (ushort*)(ws + 5 * MS);                     // 8 MiB (padded K=256)
    float*  var    = (float*)(ws + 6 * MS);                  // 65,536 B
    float*  invtr  = (float*)(ws + 6 * MS + 65536);
    float*  sqn    = (float*)(ws + 6 * MS + 66560);
    ushort* tri    = (ushort*)(ws + 6 * MS + 131072);        // 4,210,688 B
    float*  partial= (float*)(ws + 6 * MS + 131072 + 4210688);

    prep_kernel<<<4096, 256, 0, stream>>>(x, xc, var);
    finalize_norm<<<64, 256, 0, stream>>>(var, invtr, sqn);

    dim3 g1(4, 64), g2(4, 128);
    // cov: Y0 -> w0, T0 (= Z1) -> w1
    gemm_ns<0><<<g1, 256, 0, stream>>>(xc, nullptr, xc, w0, w1, invtr);
    // Y1 = Y0*T0 -> w2
    gemm_ns<2><<<g1, 256, 0, stream>>>(w0, nullptr, w1, w2, nullptr, nullptr);
    // iter2 (Y=w2, Z=w1): T = 1.5I-0.5*Z*Y -> w0 ; Y'=Y*T -> w3 ; Z'=Z*T -> w4
    gemm_ns<1><<<g1, 256, 0, stream>>>(w1, nullptr, w2, w0, nullptr, nullptr);
    gemm_ns<2><<<g2, 256, 0, stream>>>(w2, w1, w0, w3, w4, nullptr);
    // iter3 (Y=w3, Z=w4): T -> w0 ; Y' -> w1 ; Z' -> w2
    gemm_ns<1><<<g1, 256, 0, stream>>>(w4, nullptr, w3, w0, nullptr, nullptr);
    gemm_ns<2><<<g2, 256, 0, stream>>>(w3, w4, w0, w1, w2, nullptr);
    // iter4 (Y=w1, Z=w2): T -> w0 ; Y' -> w3 ; Z' -> w4
    gemm_ns<1><<<g1, 256, 0, stream>>>(w2, nullptr, w1, w0, nullptr, nullptr);
    gemm_ns<2><<<g2, 256, 0, stream>>>(w1, w2, w0, w3, w4, nullptr);
    // iter5 (Y=w3, Z=w4): T -> w0 ; tri(Y*T*sqrt(norm)) -> tri
    gemm_ns<1><<<g1, 256, 0, stream>>>(w4, nullptr, w3, w0, nullptr, nullptr);
    gemm_ns<3><<<g1, 256, 0, stream>>>(w3, nullptr, w0, tri, nullptr, sqn);

    fc_gemm<<<dim3(6, 64), 256, 0, stream>>>(tri, fcw, partial);
    fc_reduce<<<(64 * 365 + 255) / 256, 256, 0, stream>>>(partial, fcb, out);
}